// Round 2
// baseline (213.751 us; speedup 1.0000x reference)
//
#include <hip/hip_runtime.h>

// DNM dendritic layer: out[b,o] = max(0, 0.25*S - 0.05),
//   S = sum_{m,i} relu(fma(x[b,i], W[o,m,i], -q[o,m,i]))
// B=512, OUT=128, M=8, IN=512, fp32.
// VALU-bound; packed-fp32 floor: 1.5 VOP3P/elem -> ~5.1 us + mem/tail.
// Round-1 lesson: guarantee fma contraction + use v_pk_* (157TF peak needs packed).

#define BB   512
#define OUTN 128
#define MM   8
#define INN  512

typedef float f4 __attribute__((ext_vector_type(4)));
typedef float f2 __attribute__((ext_vector_type(2)));

// Block: 512 threads = 8 waves, one o per block, 128 b's (16 per wave).
// Grid: 128 o * 4 b-groups = 512 blocks = exactly 2 blocks/CU.
// __launch_bounds__(512,4): 4 waves/EU min -> VGPR cap 128 -> 16 waves/CU.
__global__ __launch_bounds__(512, 4) void dnm_kernel(
    const float* __restrict__ x,   // [B, IN]
    const float* __restrict__ W,   // [OUT, M, IN]
    const float* __restrict__ q,   // [OUT, M, IN]
    float* __restrict__ out)       // [B, OUT]
{
    __shared__ float lds_w[MM * INN];
    __shared__ float lds_q[MM * INN];

    const int tid  = threadIdx.x;
    const int o    = blockIdx.x >> 2;
    const int bgrp = blockIdx.x & 3;
    const int wave = tid >> 6;
    const int lane = tid & 63;
    const int b0   = bgrp * 128 + wave * 16;

    // Stage W[o,:,:] and q[o,:,:] (32 KB) into LDS, coalesced float4.
    {
        const f4* Wg = (const f4*)(W + (size_t)o * MM * INN);
        const f4* qg = (const f4*)(q + (size_t)o * MM * INN);
        f4* lw = (f4*)lds_w;
        f4* lq = (f4*)lds_q;
        #pragma unroll
        for (int j = 0; j < (MM * INN / 4); j += 512) {
            lw[j + tid] = Wg[j + tid];
            lq[j + tid] = qg[j + tid];
        }
    }
    __syncthreads();

    f2 acc[16];
    #pragma unroll
    for (int b = 0; b < 16; ++b) acc[b] = (f2)0.0f;

    // Lanes span i: 64 lanes * 4 floats = 256 i per chunk, 2 chunks cover IN=512.
    #pragma unroll
    for (int chunk = 0; chunk < 2; ++chunk) {
        const int i = chunk * 256 + lane * 4;

        // x[b0+b, i..i+3] for all 16 b's; reused across all 8 m's.
        f4 xv[16];
        #pragma unroll
        for (int b = 0; b < 16; ++b)
            xv[b] = *(const f4*)(x + (size_t)(b0 + b) * INN + i);

        #pragma unroll
        for (int m = 0; m < MM; ++m) {
            const f4 w4 = *(const f4*)(lds_w + m * INN + i);
            const f4 q4 = *(const f4*)(lds_q + m * INN + i);
            #pragma unroll
            for (int b = 0; b < 16; ++b) {
                // v4f32 fma -> 2x v_pk_fma_f32; max -> 2x v_pk_max_f32;
                // pair-sum + acc -> 2x v_pk_add_f32. 6 VOP3P per 4 elems.
                f4 t = __builtin_elementwise_fma(xv[b], w4, -q4);
                t = __builtin_elementwise_max(t, (f4)0.0f);
                f2 tl = __builtin_shufflevector(t, t, 0, 1);
                f2 th = __builtin_shufflevector(t, t, 2, 3);
                acc[b] += tl + th;
            }
        }
    }

    // Butterfly-reduce each acc[b] across the 64 lanes; lane b writes (b0+b, o).
    #pragma unroll
    for (int b = 0; b < 16; ++b) {
        float v = acc[b].x + acc[b].y;
        v += __shfl_xor(v, 1, 64);
        v += __shfl_xor(v, 2, 64);
        v += __shfl_xor(v, 4, 64);
        v += __shfl_xor(v, 8, 64);
        v += __shfl_xor(v, 16, 64);
        v += __shfl_xor(v, 32, 64);
        if (lane == b) {
            float r = 0.25f * v - 0.05f;   // K*K*S - K*QS
            out[(size_t)(b0 + b) * OUTN + o] = fmaxf(r, 0.0f);
        }
    }
}

extern "C" void kernel_launch(void* const* d_in, const int* in_sizes, int n_in,
                              void* d_out, int out_size, void* d_ws, size_t ws_size,
                              hipStream_t stream) {
    const float* x = (const float*)d_in[0];
    const float* W = (const float*)d_in[1];
    const float* q = (const float*)d_in[2];
    float* out = (float*)d_out;
    dim3 grid(OUTN * 4);   // 128 o * 4 b-groups = 512 blocks (2/CU)
    dim3 block(512);
    dnm_kernel<<<grid, block, 0, stream>>>(x, W, q, out);
}

// Round 4
// 81.448 us; speedup vs baseline: 2.6244x; 2.6244x over previous
//
#include <hip/hip_runtime.h>

// DNM dendritic layer: out[b,o] = max(0, 0.25*S - 0.05),
//   S = sum_{m,i} relu(fma(x[b,i], W[o,m,i], -q[o,m,i]))
// B=512, OUT=128, M=8, IN=512, fp32.
// VALU-bound. Packed-fp32 floor: 6 VOP3P per (4 elems) -> ~5.1 us device-wide.
// R2 lesson: VGPR caps from launch_bounds 2nd arg -> spills -> 380MB scratch
//   traffic -> 214us. R3 lesson: chunk-loop unroll pipelining re-inflated the
//   live set past the cap -> spilled again (same 214us fingerprint) AND broke
//   graph-replay correctness. This round: NO vgpr cap, NO chunk unroll.

#define OUTN 128
#define MM   8
#define INN  512

typedef float f4 __attribute__((ext_vector_type(4)));

// Block: 256 threads = 4 waves, one o per block, 32 b's (8 per wave).
// Grid: 128 o * 16 b-groups = 2048 blocks. LDS 32 KB -> 5 blocks/CU.
// __launch_bounds__(256) only: no VGPR cap, zero spill risk; LDS bounds
// occupancy anyway (20 waves/CU at ~110 VGPR).
__global__ __launch_bounds__(256) void dnm_kernel(
    const float* __restrict__ x,   // [B, IN]
    const float* __restrict__ W,   // [OUT, M, IN]
    const float* __restrict__ q,   // [OUT, M, IN]
    float* __restrict__ out)       // [B, OUT]
{
    __shared__ float lds_w[MM * INN];
    __shared__ float lds_q[MM * INN];

    const int tid  = threadIdx.x;
    const int o    = blockIdx.x >> 4;
    const int bgrp = blockIdx.x & 15;
    const int wave = tid >> 6;
    const int lane = tid & 63;
    const int b0   = bgrp * 32 + wave * 8;

    // Stage W[o,:,:] and q[o,:,:] (32 KB) into LDS, coalesced float4.
    {
        const f4* Wg = (const f4*)(W + (size_t)o * MM * INN);
        const f4* qg = (const f4*)(q + (size_t)o * MM * INN);
        f4* lw = (f4*)lds_w;
        f4* lq = (f4*)lds_q;
        #pragma unroll
        for (int j = 0; j < (MM * INN / 4); j += 256) {
            lw[j + tid] = Wg[j + tid];
            lq[j + tid] = qg[j + tid];
        }
    }
    __syncthreads();

    f4 acc[8];
    #pragma unroll
    for (int b = 0; b < 8; ++b) acc[b] = (f4)0.0f;

    // Lanes span i: 64 lanes * 4 floats = 256 i per chunk, 2 chunks cover
    // IN=512. unroll 1: keep only one chunk's xv live (32 VGPRs) — do NOT
    // let the scheduler pipeline both chunks (that spilled in R3).
    #pragma unroll 1
    for (int chunk = 0; chunk < 2; ++chunk) {
        const int i = chunk * 256 + lane * 4;

        // x[b0+b, i..i+3] for 8 b's; reused across all 8 m's. 32 VGPRs.
        f4 xv[8];
        #pragma unroll
        for (int b = 0; b < 8; ++b)
            xv[b] = *(const f4*)(x + (size_t)(b0 + b) * INN + i);

        #pragma unroll
        for (int m = 0; m < MM; ++m) {
            const f4 w4 = *(const f4*)(lds_w + m * INN + i);
            const f4 q4 = *(const f4*)(lds_q + m * INN + i);
            #pragma unroll
            for (int b = 0; b < 8; ++b) {
                // 2x v_pk_fma_f32 + 2x v_pk_max_f32 + 2x v_pk_add_f32
                // = 6 VOP3P per (b, m, 4 i-elems).
                f4 t = __builtin_elementwise_fma(xv[b], w4, -q4);
                t = __builtin_elementwise_max(t, (f4)0.0f);
                acc[b] += t;
            }
        }
    }

    // Butterfly-reduce each acc[b] across the 64 lanes; lane b writes (b0+b, o).
    #pragma unroll
    for (int b = 0; b < 8; ++b) {
        float v = (acc[b].x + acc[b].y) + (acc[b].z + acc[b].w);
        v += __shfl_xor(v, 1, 64);
        v += __shfl_xor(v, 2, 64);
        v += __shfl_xor(v, 4, 64);
        v += __shfl_xor(v, 8, 64);
        v += __shfl_xor(v, 16, 64);
        v += __shfl_xor(v, 32, 64);
        if (lane == b) {
            float r = 0.25f * v - 0.05f;   // K*K*S - K*QS
            out[(size_t)(b0 + b) * OUTN + o] = fmaxf(r, 0.0f);
        }
    }
}

extern "C" void kernel_launch(void* const* d_in, const int* in_sizes, int n_in,
                              void* d_out, int out_size, void* d_ws, size_t ws_size,
                              hipStream_t stream) {
    const float* x = (const float*)d_in[0];
    const float* W = (const float*)d_in[1];
    const float* q = (const float*)d_in[2];
    float* out = (float*)d_out;
    dim3 grid(OUTN * 16);   // 128 o * 16 b-groups = 2048 blocks
    dim3 block(256);
    dnm_kernel<<<grid, block, 0, stream>>>(x, W, q, out);
}